// Round 6
// baseline (397.323 us; speedup 1.0000x reference)
//
#include <hip/hip_runtime.h>
#include <hip/hip_bf16.h>
#include <hip/hip_fp16.h>

#define IN_DIM 128
#define C_DIM 64

typedef __attribute__((ext_vector_type(8))) short bf16x8;
typedef __attribute__((ext_vector_type(4))) float f32x4;

__device__ __forceinline__ short f2b(float f) {
    unsigned u = __float_as_uint(f);
    unsigned r = (u + 0x7FFFu + ((u >> 16) & 1u)) >> 16;   // RNE to bf16
    return (short)r;
}
__device__ __forceinline__ float h2f_lo(int p) {
    return __half2float(__ushort_as_half((unsigned short)(p & 0xFFFF)));
}
__device__ __forceinline__ float h2f_hi(int p) {
    return __half2float(__ushort_as_half((unsigned short)((unsigned)p >> 16)));
}

// ---------------------------------------------------------------------------
// K1: xp = x @ W via MFMA bf16, attention-dot epilogue fused. (unchanged R5)
// ---------------------------------------------------------------------------
__global__ __launch_bounds__(256) void k_gemm(
    const float* __restrict__ x,
    const float* __restrict__ W,
    const float* __restrict__ att_src,
    const float* __restrict__ att_dst,
    float* __restrict__ xp,
    float* __restrict__ s_src,
    float* __restrict__ s_dst,
    int n)
{
    __shared__ short WT[C_DIM][136];

    const int t = threadIdx.x;
    for (int i = t; i < IN_DIM * C_DIM; i += 256) {
        int k = i >> 6, nn = i & 63;
        WT[nn][k] = f2b(W[i]);
    }
    __syncthreads();

    const int lane = t & 63;
    const int wv   = t >> 6;
    const int base = (blockIdx.x * 4 + wv) * 16;
    if (base >= n) return;

    const int m    = lane & 15;
    const int quad = lane >> 4;
    int rowA = base + m;
    if (rowA >= n) rowA = n - 1;
    const float* xr = x + (size_t)rowA * IN_DIM + quad * 8;

    f32x4 acc[4] = {{0,0,0,0},{0,0,0,0},{0,0,0,0},{0,0,0,0}};

    #pragma unroll
    for (int ks = 0; ks < 4; ++ks) {
        float4 f0 = *(const float4*)(xr + ks * 32);
        float4 f1 = *(const float4*)(xr + ks * 32 + 4);
        bf16x8 a;
        a[0] = f2b(f0.x); a[1] = f2b(f0.y); a[2] = f2b(f0.z); a[3] = f2b(f0.w);
        a[4] = f2b(f1.x); a[5] = f2b(f1.y); a[6] = f2b(f1.z); a[7] = f2b(f1.w);
        #pragma unroll
        for (int nt = 0; nt < 4; ++nt) {
            bf16x8 b = *(const bf16x8*)&WT[nt * 16 + m][ks * 32 + quad * 8];
            acc[nt] = __builtin_amdgcn_mfma_f32_16x16x32_bf16(a, b, acc[nt], 0, 0, 0);
        }
    }

    float asv[4], adv[4];
    #pragma unroll
    for (int nt = 0; nt < 4; ++nt) {
        asv[nt] = att_src[nt * 16 + m];
        adv[nt] = att_dst[nt * 16 + m];
    }
    #pragma unroll
    for (int q = 0; q < 4; ++q) {
        float vs = 0.f, vd = 0.f;
        #pragma unroll
        for (int nt = 0; nt < 4; ++nt) {
            vs = fmaf(acc[nt][q], asv[nt], vs);
            vd = fmaf(acc[nt][q], adv[nt], vd);
        }
        #pragma unroll
        for (int off = 8; off > 0; off >>= 1) {
            vs += __shfl_xor(vs, off, 64);
            vd += __shfl_xor(vd, off, 64);
        }
        int r = base + quad * 4 + q;
        if (m == 0 && r < n) { s_src[r] = vs; s_dst[r] = vd; }
    }

    #pragma unroll
    for (int nt = 0; nt < 4; ++nt)
        #pragma unroll
        for (int q = 0; q < 4; ++q) {
            int r = base + quad * 4 + q;
            if (r < n) xp[(size_t)r * C_DIM + nt * 16 + m] = acc[nt][q];
        }
}

// ---------------------------------------------------------------------------
// K2: degree count, per-XCD private copy. 4 edges/thread (int4).
// Index mapping MUST be identical to k_place (same grid & i0 formula).
// ---------------------------------------------------------------------------
__global__ __launch_bounds__(256) void k_deg(
    const int* __restrict__ ei_dst,
    int* __restrict__ deg_x,
    int e, int n)
{
    int* my = deg_x + (size_t)(blockIdx.x & 7) * n;
    const int i0 = (blockIdx.x * 256 + threadIdx.x) * 4;
    if (i0 + 3 < e) {
        int4 dv = *(const int4*)&ei_dst[i0];
        atomicAdd(&my[dv.x], 1);
        atomicAdd(&my[dv.y], 1);
        atomicAdd(&my[dv.z], 1);
        atomicAdd(&my[dv.w], 1);
    } else {
        for (int i = i0; i < e; ++i) atomicAdd(&my[ei_dst[i]], 1);
    }
}

// ---------------------------------------------------------------------------
// Scan over deg_x LINEARLY (xcd-major): each XCD's slot region is contiguous,
// so k_place's stores stay inside its own ~1.6MB L2-resident window.
// ---------------------------------------------------------------------------
__global__ __launch_bounds__(1024) void k_scan1(
    const int* __restrict__ deg_x, int* __restrict__ bsum, int total)
{
    const int t = threadIdx.x;
    const int j = blockIdx.x * 1024 + t;
    int v = (j < total) ? deg_x[j] : 0;
    #pragma unroll
    for (int off = 32; off > 0; off >>= 1) v += __shfl_xor(v, off, 64);
    __shared__ int ws[16];
    if ((t & 63) == 0) ws[t >> 6] = v;
    __syncthreads();
    if (t == 0) {
        int s = 0;
        #pragma unroll
        for (int k = 0; k < 16; ++k) s += ws[k];
        bsum[blockIdx.x] = s;
    }
}

__global__ __launch_bounds__(1024) void k_scan2(
    const int* __restrict__ bsum, int* __restrict__ bpre,
    int nb, int* __restrict__ offs_x, int total, int e)
{
    __shared__ int buf[1024];
    const int t = threadIdx.x;
    int v = (t < nb) ? bsum[t] : 0;
    buf[t] = v;
    __syncthreads();
    #pragma unroll
    for (int off = 1; off < 1024; off <<= 1) {
        int add = (t >= off) ? buf[t - off] : 0;
        __syncthreads();
        buf[t] += add;
        __syncthreads();
    }
    if (t < nb) bpre[t] = buf[t] - v;   // exclusive
    if (t == 0) offs_x[total] = e;      // sentinel
}

__global__ __launch_bounds__(1024) void k_scan3(
    const int* __restrict__ deg_x, const int* __restrict__ bpre,
    int* __restrict__ cursor_x, int* __restrict__ offs_x, int total)
{
    __shared__ int buf[1024];
    const int t = threadIdx.x;
    const int j = blockIdx.x * 1024 + t;
    int v = (j < total) ? deg_x[j] : 0;
    buf[t] = v;
    __syncthreads();
    #pragma unroll
    for (int off = 1; off < 1024; off <<= 1) {
        int add = (t >= off) ? buf[t - off] : 0;
        __syncthreads();
        buf[t] += add;
        __syncthreads();
    }
    if (j < total) {
        int g = bpre[blockIdx.x] + buf[t] - v;
        cursor_x[j] = g;
        offs_x[j]   = g;
    }
}

// ---------------------------------------------------------------------------
// K3: place edges into [xcd][dst-sorted] slots. Stores + cursor atomics are
// confined to this XCD's contiguous window -> L2-resident until full.
// ---------------------------------------------------------------------------
__global__ __launch_bounds__(256) void k_place(
    const int* __restrict__ ei_src,
    const int* __restrict__ ei_dst,
    const float* __restrict__ beta,
    const float* __restrict__ s_src,
    const float* __restrict__ s_dst,
    int* __restrict__ cursor_x,
    int2* __restrict__ srcg,
    int e, int n)
{
    int* cur = cursor_x + (size_t)(blockIdx.x & 7) * n;
    const int i0 = (blockIdx.x * 256 + threadIdx.x) * 4;

    if (i0 + 3 < e) {
        int4   sv = *(const int4*)&ei_src[i0];
        int4   dv = *(const int4*)&ei_dst[i0];
        float4 bt = *(const float4*)&beta[i0];
        #pragma unroll
        for (int k = 0; k < 4; ++k) {
            int s = (k == 0) ? sv.x : (k == 1) ? sv.y : (k == 2) ? sv.z : sv.w;
            int d = (k == 0) ? dv.x : (k == 1) ? dv.y : (k == 2) ? dv.z : dv.w;
            float b = (k == 0) ? bt.x : (k == 1) ? bt.y : (k == 2) ? bt.z : bt.w;
            float z  = s_src[s] + s_dst[d];
            float ee = __expf(1.f / (1.f + __expf(-z)));
            unsigned pk = (unsigned)__half_as_ushort(__float2half(ee))
                        | ((unsigned)__half_as_ushort(__float2half(b)) << 16);
            int slot = atomicAdd(&cur[d], 1);
            srcg[slot] = make_int2(s, (int)pk);
        }
    } else {
        for (int i = i0; i < e; ++i) {
            int s = ei_src[i];
            int d = ei_dst[i];
            float z  = s_src[s] + s_dst[d];
            float ee = __expf(1.f / (1.f + __expf(-z)));
            unsigned pk = (unsigned)__half_as_ushort(__float2half(ee))
                        | ((unsigned)__half_as_ushort(__float2half(beta[i])) << 16);
            int slot = atomicAdd(&cur[d], 1);
            srcg[slot] = make_int2(s, (int)pk);
        }
    }
}

// ---------------------------------------------------------------------------
// K4: segmented reduction, wave per dst, lane = channel. Single pass:
//   accA = sum ee*xp[s], accB = sum beta*xp[s], ps = sum ee  (broadcast adds)
//   out = (lam/ps)*accA + (1-lam)*accB
// 8 sub-segments per dst (one per XCD window).
// ---------------------------------------------------------------------------
__global__ __launch_bounds__(256) void k_seg(
    const int* __restrict__ offs_x,
    const int2* __restrict__ srcg,
    const float* __restrict__ xp,
    const float* __restrict__ lam01,
    float* __restrict__ out,
    int n)
{
    const int lane = threadIdx.x & 63;
    const int d    = (blockIdx.x * 256 + threadIdx.x) >> 6;
    if (d >= n) return;

    const float lam = lam01[0];
    const float oml = 1.f - lam;

    float accA = 0.f, accB = 0.f, ps = 0.f;

    #pragma unroll
    for (int xc = 0; xc < 8; ++xc) {
        const int lo = offs_x[xc * n + d];
        const int hi = offs_x[xc * n + d + 1];
        for (int base = lo; base < hi; base += 64) {
            const int cnt = min(64, hi - base);
            int svv = 0, pkv = 0;
            if (lane < cnt) {
                int2 v = srcg[base + lane];
                svv = v.x; pkv = v.y;
            }
            int j = 0;
            for (; j + 2 <= cnt; j += 2) {
                int s0 = __builtin_amdgcn_readlane(svv, j);
                int p0 = __builtin_amdgcn_readlane(pkv, j);
                int s1 = __builtin_amdgcn_readlane(svv, j + 1);
                int p1 = __builtin_amdgcn_readlane(pkv, j + 1);
                float x0 = xp[(size_t)s0 * C_DIM + lane];
                float x1 = xp[(size_t)s1 * C_DIM + lane];
                float e0 = h2f_lo(p0), b0 = h2f_hi(p0);
                float e1 = h2f_lo(p1), b1 = h2f_hi(p1);
                accA = fmaf(x0, e0, accA);
                accB = fmaf(x0, b0, accB);
                ps  += e0;
                accA = fmaf(x1, e1, accA);
                accB = fmaf(x1, b1, accB);
                ps  += e1;
            }
            if (j < cnt) {
                int s0 = __builtin_amdgcn_readlane(svv, j);
                int p0 = __builtin_amdgcn_readlane(pkv, j);
                float x0 = xp[(size_t)s0 * C_DIM + lane];
                float e0 = h2f_lo(p0), b0 = h2f_hi(p0);
                accA = fmaf(x0, e0, accA);
                accB = fmaf(x0, b0, accB);
                ps  += e0;
            }
        }
    }

    const float r = lam / (ps + 1e-16f);
    out[(size_t)d * C_DIM + lane] = r * accA + oml * accB;
}

extern "C" void kernel_launch(void* const* d_in, const int* in_sizes, int n_in,
                              void* d_out, int out_size, void* d_ws, size_t ws_size,
                              hipStream_t stream)
{
    const float* x       = (const float*)d_in[0];
    const int*   ei      = (const int*)d_in[1];
    const float* beta    = (const float*)d_in[2];
    const float* lam01   = (const float*)d_in[3];
    const float* W       = (const float*)d_in[4];
    const float* att_src = (const float*)d_in[5];
    const float* att_dst = (const float*)d_in[6];
    float*       out     = (float*)d_out;

    const int n = in_sizes[0] / IN_DIM;   // 100000
    const int e = in_sizes[2];            // 1600000

    // workspace (4B units); xp count is even so srcg stays 8B-aligned
    float* xp       = (float*)d_ws;                       // n*64
    int2*  srcg     = (int2*)(xp + (size_t)n * C_DIM);    // e int2
    float* s_src    = (float*)(srcg + e);                 // n
    float* s_dst    = s_src + n;                          // n
    int*   deg_x    = (int*)(s_dst + n);                  // 8n (memset 0)
    int*   cursor_x = deg_x + (size_t)8 * n;              // 8n
    int*   offs_x   = cursor_x + (size_t)8 * n;           // 8n+1
    int*   bsum     = offs_x + (size_t)8 * n + 2;         // 1024
    int*   bpre     = bsum + 1024;                        // 1024

    const int total = 8 * n;
    const int nb    = (total + 1023) / 1024;              // 782 <= 1024
    const int ge    = (e + 1023) / 1024;                  // edge grid (x4/thread)

    hipMemsetAsync(deg_x, 0, (size_t)total * sizeof(int), stream);

    k_gemm <<<(n + 63) / 64, 256, 0, stream>>>(x, W, att_src, att_dst, xp, s_src, s_dst, n);
    k_deg  <<<ge, 256, 0, stream>>>(ei + e, deg_x, e, n);
    k_scan1<<<nb, 1024, 0, stream>>>(deg_x, bsum, total);
    k_scan2<<<1, 1024, 0, stream>>>(bsum, bpre, nb, offs_x, total, e);
    k_scan3<<<nb, 1024, 0, stream>>>(deg_x, bpre, cursor_x, offs_x, total);
    k_place<<<ge, 256, 0, stream>>>(ei, ei + e, beta, s_src, s_dst, cursor_x, srcg, e, n);
    k_seg  <<<(n + 3) / 4, 256, 0, stream>>>(offs_x, srcg, xp, lam01, out, n);
}

// Round 7
// 334.856 us; speedup vs baseline: 1.1865x; 1.1865x over previous
//
#include <hip/hip_runtime.h>
#include <hip/hip_bf16.h>
#include <hip/hip_fp16.h>

#define IN_DIM 128
#define C_DIM 64

typedef __attribute__((ext_vector_type(8))) short bf16x8;
typedef __attribute__((ext_vector_type(4))) float f32x4;

__device__ __forceinline__ short f2b(float f) {
    unsigned u = __float_as_uint(f);
    unsigned r = (u + 0x7FFFu + ((u >> 16) & 1u)) >> 16;   // RNE to bf16
    return (short)r;
}
__device__ __forceinline__ float h2f_lo(int p) {
    return __half2float(__ushort_as_half((unsigned short)(p & 0xFFFF)));
}
__device__ __forceinline__ float h2f_hi(int p) {
    return __half2float(__ushort_as_half((unsigned short)((unsigned)p >> 16)));
}

// ---------------------------------------------------------------------------
// K1: xp = x @ W via MFMA bf16, attention-dot epilogue fused.
// xp now stored as bf16 (halves k_seg gather bytes + our write traffic).
// ---------------------------------------------------------------------------
__global__ __launch_bounds__(256) void k_gemm(
    const float* __restrict__ x,
    const float* __restrict__ W,
    const float* __restrict__ att_src,
    const float* __restrict__ att_dst,
    unsigned short* __restrict__ xp_bf,
    float* __restrict__ s_src,
    float* __restrict__ s_dst,
    int n)
{
    __shared__ short WT[C_DIM][136];

    const int t = threadIdx.x;
    for (int i = t; i < IN_DIM * C_DIM; i += 256) {
        int k = i >> 6, nn = i & 63;
        WT[nn][k] = f2b(W[i]);
    }
    __syncthreads();

    const int lane = t & 63;
    const int wv   = t >> 6;
    const int base = (blockIdx.x * 4 + wv) * 16;
    if (base >= n) return;

    const int m    = lane & 15;
    const int quad = lane >> 4;
    int rowA = base + m;
    if (rowA >= n) rowA = n - 1;
    const float* xr = x + (size_t)rowA * IN_DIM + quad * 8;

    f32x4 acc[4] = {{0,0,0,0},{0,0,0,0},{0,0,0,0},{0,0,0,0}};

    #pragma unroll
    for (int ks = 0; ks < 4; ++ks) {
        float4 f0 = *(const float4*)(xr + ks * 32);
        float4 f1 = *(const float4*)(xr + ks * 32 + 4);
        bf16x8 a;
        a[0] = f2b(f0.x); a[1] = f2b(f0.y); a[2] = f2b(f0.z); a[3] = f2b(f0.w);
        a[4] = f2b(f1.x); a[5] = f2b(f1.y); a[6] = f2b(f1.z); a[7] = f2b(f1.w);
        #pragma unroll
        for (int nt = 0; nt < 4; ++nt) {
            bf16x8 b = *(const bf16x8*)&WT[nt * 16 + m][ks * 32 + quad * 8];
            acc[nt] = __builtin_amdgcn_mfma_f32_16x16x32_bf16(a, b, acc[nt], 0, 0, 0);
        }
    }

    float asv[4], adv[4];
    #pragma unroll
    for (int nt = 0; nt < 4; ++nt) {
        asv[nt] = att_src[nt * 16 + m];
        adv[nt] = att_dst[nt * 16 + m];
    }
    #pragma unroll
    for (int q = 0; q < 4; ++q) {
        float vs = 0.f, vd = 0.f;
        #pragma unroll
        for (int nt = 0; nt < 4; ++nt) {
            vs = fmaf(acc[nt][q], asv[nt], vs);
            vd = fmaf(acc[nt][q], adv[nt], vd);
        }
        #pragma unroll
        for (int off = 8; off > 0; off >>= 1) {
            vs += __shfl_xor(vs, off, 64);
            vd += __shfl_xor(vd, off, 64);
        }
        int r = base + quad * 4 + q;
        if (m == 0 && r < n) { s_src[r] = vs; s_dst[r] = vd; }
    }

    #pragma unroll
    for (int nt = 0; nt < 4; ++nt)
        #pragma unroll
        for (int q = 0; q < 4; ++q) {
            int r = base + quad * 4 + q;
            if (r < n)
                xp_bf[(size_t)r * C_DIM + nt * 16 + m] = (unsigned short)f2b(acc[nt][q]);
        }
}

// ---------------------------------------------------------------------------
// K2: degree count, per-XCD private copy. 4 edges/thread (int4).
// Index mapping MUST be identical to k_place (same grid & i0 formula).
// ---------------------------------------------------------------------------
__global__ __launch_bounds__(256) void k_deg(
    const int* __restrict__ ei_dst,
    int* __restrict__ deg_x,
    int e, int n)
{
    int* my = deg_x + (size_t)(blockIdx.x & 7) * n;
    const int i0 = (blockIdx.x * 256 + threadIdx.x) * 4;
    if (i0 + 3 < e) {
        int4 dv = *(const int4*)&ei_dst[i0];
        atomicAdd(&my[dv.x], 1);
        atomicAdd(&my[dv.y], 1);
        atomicAdd(&my[dv.z], 1);
        atomicAdd(&my[dv.w], 1);
    } else {
        for (int i = i0; i < e; ++i) atomicAdd(&my[ei_dst[i]], 1);
    }
}

// ---------------------------------------------------------------------------
// Linear scan over deg_x (xcd-major) -> cursor_x / offs_x, sentinel at 8n.
// ---------------------------------------------------------------------------
__global__ __launch_bounds__(1024) void k_scan1(
    const int* __restrict__ deg_x, int* __restrict__ bsum, int total)
{
    const int t = threadIdx.x;
    const int j = blockIdx.x * 1024 + t;
    int v = (j < total) ? deg_x[j] : 0;
    #pragma unroll
    for (int off = 32; off > 0; off >>= 1) v += __shfl_xor(v, off, 64);
    __shared__ int ws[16];
    if ((t & 63) == 0) ws[t >> 6] = v;
    __syncthreads();
    if (t == 0) {
        int s = 0;
        #pragma unroll
        for (int k = 0; k < 16; ++k) s += ws[k];
        bsum[blockIdx.x] = s;
    }
}

__global__ __launch_bounds__(1024) void k_scan2(
    const int* __restrict__ bsum, int* __restrict__ bpre,
    int nb, int* __restrict__ offs_x, int total, int e)
{
    __shared__ int buf[1024];
    const int t = threadIdx.x;
    int v = (t < nb) ? bsum[t] : 0;
    buf[t] = v;
    __syncthreads();
    #pragma unroll
    for (int off = 1; off < 1024; off <<= 1) {
        int add = (t >= off) ? buf[t - off] : 0;
        __syncthreads();
        buf[t] += add;
        __syncthreads();
    }
    if (t < nb) bpre[t] = buf[t] - v;   // exclusive
    if (t == 0) offs_x[total] = e;      // sentinel
}

__global__ __launch_bounds__(1024) void k_scan3(
    const int* __restrict__ deg_x, const int* __restrict__ bpre,
    int* __restrict__ cursor_x, int* __restrict__ offs_x, int total)
{
    __shared__ int buf[1024];
    const int t = threadIdx.x;
    const int j = blockIdx.x * 1024 + t;
    int v = (j < total) ? deg_x[j] : 0;
    buf[t] = v;
    __syncthreads();
    #pragma unroll
    for (int off = 1; off < 1024; off <<= 1) {
        int add = (t >= off) ? buf[t - off] : 0;
        __syncthreads();
        buf[t] += add;
        __syncthreads();
    }
    if (j < total) {
        int g = bpre[blockIdx.x] + buf[t] - v;
        cursor_x[j] = g;
        offs_x[j]   = g;
    }
}

// ---------------------------------------------------------------------------
// K3: place edges into [xcd][dst-sorted] slots (stores + cursor atomics are
// confined to this XCD's contiguous ~1.6MB window -> L2-resident).
// ---------------------------------------------------------------------------
__global__ __launch_bounds__(256) void k_place(
    const int* __restrict__ ei_src,
    const int* __restrict__ ei_dst,
    const float* __restrict__ beta,
    const float* __restrict__ s_src,
    const float* __restrict__ s_dst,
    int* __restrict__ cursor_x,
    int2* __restrict__ srcg,
    int e, int n)
{
    int* cur = cursor_x + (size_t)(blockIdx.x & 7) * n;
    const int i0 = (blockIdx.x * 256 + threadIdx.x) * 4;

    if (i0 + 3 < e) {
        int4   sv = *(const int4*)&ei_src[i0];
        int4   dv = *(const int4*)&ei_dst[i0];
        float4 bt = *(const float4*)&beta[i0];
        #pragma unroll
        for (int k = 0; k < 4; ++k) {
            int s = (k == 0) ? sv.x : (k == 1) ? sv.y : (k == 2) ? sv.z : sv.w;
            int d = (k == 0) ? dv.x : (k == 1) ? dv.y : (k == 2) ? dv.z : dv.w;
            float b = (k == 0) ? bt.x : (k == 1) ? bt.y : (k == 2) ? bt.z : bt.w;
            float z  = s_src[s] + s_dst[d];
            float ee = __expf(1.f / (1.f + __expf(-z)));
            unsigned pk = (unsigned)__half_as_ushort(__float2half(ee))
                        | ((unsigned)__half_as_ushort(__float2half(b)) << 16);
            int slot = atomicAdd(&cur[d], 1);
            srcg[slot] = make_int2(s, (int)pk);
        }
    } else {
        for (int i = i0; i < e; ++i) {
            int s = ei_src[i];
            int d = ei_dst[i];
            float z  = s_src[s] + s_dst[d];
            float ee = __expf(1.f / (1.f + __expf(-z)));
            unsigned pk = (unsigned)__half_as_ushort(__float2half(ee))
                        | ((unsigned)__half_as_ushort(__float2half(beta[i])) << 16);
            int slot = atomicAdd(&cur[d], 1);
            srcg[slot] = make_int2(s, (int)pk);
        }
    }
}

// ---------------------------------------------------------------------------
// K4: segmented reduction, wave per dst, lane = channel.
// Flattened 8-window indexing: 16 lanes fetch all (lo,hi) in ONE round;
// per-lane (window,slot) via unrolled prefix select; one coalesced srcg
// round per 64 edges. Single pass:
//   accA = sum ee*xp[s], accB = sum beta*xp[s], ps = sum ee
//   out = (lam/ps)*accA + (1-lam)*accB
// ---------------------------------------------------------------------------
__global__ __launch_bounds__(256) void k_seg(
    const int* __restrict__ offs_x,
    const int2* __restrict__ srcg,
    const unsigned short* __restrict__ xp_bf,
    const float* __restrict__ lam01,
    float* __restrict__ out,
    int n)
{
    const int lane = threadIdx.x & 63;
    const int d    = (blockIdx.x * 256 + threadIdx.x) >> 6;
    if (d >= n) return;

    // one load round: lanes 0..7 -> lo[xc], lanes 8..15 -> hi[xc]
    int ov = 0;
    if (lane < 16)
        ov = offs_x[(size_t)(lane & 7) * n + d + (lane >> 3)];

    int lo[8], p[9];
    p[0] = 0;
    #pragma unroll
    for (int xc = 0; xc < 8; ++xc) {
        lo[xc]    = __builtin_amdgcn_readlane(ov, xc);
        int hi    = __builtin_amdgcn_readlane(ov, xc + 8);
        p[xc + 1] = p[xc] + (hi - lo[xc]);
    }
    const int T = p[8];

    const float lam = lam01[0];
    const float oml = 1.f - lam;

    float accA = 0.f, accB = 0.f, ps = 0.f;

    for (int base = 0; base < T; base += 64) {
        const int idx = base + lane;
        int sv = 0, pk = 0;
        if (idx < T) {
            int addr = 0;
            #pragma unroll
            for (int xc = 0; xc < 8; ++xc)
                if (idx >= p[xc] && idx < p[xc + 1]) addr = lo[xc] + (idx - p[xc]);
            int2 v = srcg[addr];
            sv = v.x; pk = v.y;
        }
        const int m = min(64, T - base);
        int j = 0;
        for (; j + 2 <= m; j += 2) {
            int s0 = __builtin_amdgcn_readlane(sv, j);
            int p0 = __builtin_amdgcn_readlane(pk, j);
            int s1 = __builtin_amdgcn_readlane(sv, j + 1);
            int p1 = __builtin_amdgcn_readlane(pk, j + 1);
            float x0 = __uint_as_float((unsigned)xp_bf[(size_t)s0 * C_DIM + lane] << 16);
            float x1 = __uint_as_float((unsigned)xp_bf[(size_t)s1 * C_DIM + lane] << 16);
            float e0 = h2f_lo(p0), b0 = h2f_hi(p0);
            float e1 = h2f_lo(p1), b1 = h2f_hi(p1);
            accA = fmaf(x0, e0, accA);
            accB = fmaf(x0, b0, accB);
            ps  += e0;
            accA = fmaf(x1, e1, accA);
            accB = fmaf(x1, b1, accB);
            ps  += e1;
        }
        if (j < m) {
            int s0 = __builtin_amdgcn_readlane(sv, j);
            int p0 = __builtin_amdgcn_readlane(pk, j);
            float x0 = __uint_as_float((unsigned)xp_bf[(size_t)s0 * C_DIM + lane] << 16);
            float e0 = h2f_lo(p0), b0 = h2f_hi(p0);
            accA = fmaf(x0, e0, accA);
            accB = fmaf(x0, b0, accB);
            ps  += e0;
        }
    }

    const float r = lam / (ps + 1e-16f);
    out[(size_t)d * C_DIM + lane] = r * accA + oml * accB;
}

extern "C" void kernel_launch(void* const* d_in, const int* in_sizes, int n_in,
                              void* d_out, int out_size, void* d_ws, size_t ws_size,
                              hipStream_t stream)
{
    const float* x       = (const float*)d_in[0];
    const int*   ei      = (const int*)d_in[1];
    const float* beta    = (const float*)d_in[2];
    const float* lam01   = (const float*)d_in[3];
    const float* W       = (const float*)d_in[4];
    const float* att_src = (const float*)d_in[5];
    const float* att_dst = (const float*)d_in[6];
    float*       out     = (float*)d_out;

    const int n = in_sizes[0] / IN_DIM;   // 100000
    const int e = in_sizes[2];            // 1600000

    // workspace (srcg first: 8B alignment)
    int2*           srcg     = (int2*)d_ws;                    // e int2
    unsigned short* xp_bf    = (unsigned short*)(srcg + e);    // n*64 ushort
    float*          s_src    = (float*)(xp_bf + (size_t)n * C_DIM);  // n
    float*          s_dst    = s_src + n;                      // n
    int*            deg_x    = (int*)(s_dst + n);              // 8n (memset 0)
    int*            cursor_x = deg_x + (size_t)8 * n;          // 8n
    int*            offs_x   = cursor_x + (size_t)8 * n;       // 8n+1
    int*            bsum     = offs_x + (size_t)8 * n + 2;     // 1024
    int*            bpre     = bsum + 1024;                    // 1024

    const int total = 8 * n;
    const int nb    = (total + 1023) / 1024;                   // 782 <= 1024
    const int ge    = (e + 1023) / 1024;                       // edge grid (x4/thread)

    hipMemsetAsync(deg_x, 0, (size_t)total * sizeof(int), stream);

    k_gemm <<<(n + 63) / 64, 256, 0, stream>>>(x, W, att_src, att_dst, xp_bf, s_src, s_dst, n);
    k_deg  <<<ge, 256, 0, stream>>>(ei + e, deg_x, e, n);
    k_scan1<<<nb, 1024, 0, stream>>>(deg_x, bsum, total);
    k_scan2<<<1, 1024, 0, stream>>>(bsum, bpre, nb, offs_x, total, e);
    k_scan3<<<nb, 1024, 0, stream>>>(deg_x, bpre, cursor_x, offs_x, total);
    k_place<<<ge, 256, 0, stream>>>(ei, ei + e, beta, s_src, s_dst, cursor_x, srcg, e, n);
    k_seg  <<<(n + 3) / 4, 256, 0, stream>>>(offs_x, srcg, xp_bf, lam01, out, n);
}